// Round 10
// baseline (47.052 us; speedup 1.0000x reference)
//
#include <hip/hip_runtime.h>

#define BATCH 8
#define NUM_GENES 20000
#define FEAT 64

__device__ __forceinline__ unsigned bf_round(float f) {
    unsigned u = __float_as_uint(f);
    return (u + 0x7FFFu + ((u >> 16) & 1u)) >> 16;   // RNE to bf16
}

// Pass 1 (fused): convert gene f32 -> bf16 plane in d_ws (RNE), and find
// segment start offsets. Both grid-stride; 2048 blocks saturate HBM.
__global__ __launch_bounds__(256)
void convert_and_starts_kernel(const float* __restrict__ gene,
                               const int*   __restrict__ segment_ids,
                               unsigned short* __restrict__ bf,
                               int* __restrict__ starts,
                               int total, int nconv8)
{
    const int tid = blockIdx.x * 256 + threadIdx.x;
    const int nth = gridDim.x * 256;

    const float4* g4 = reinterpret_cast<const float4*>(gene);
    uint4*        o4 = reinterpret_cast<uint4*>(bf);
    for (int i = tid; i < nconv8; i += nth) {       // 8 floats -> 8 bf16
        const float4 a = g4[2 * i];
        const float4 c = g4[2 * i + 1];
        uint4 o;
        o.x = bf_round(a.x) | (bf_round(a.y) << 16);
        o.y = bf_round(a.z) | (bf_round(a.w) << 16);
        o.z = bf_round(c.x) | (bf_round(c.y) << 16);
        o.w = bf_round(c.z) | (bf_round(c.w) << 16);
        o4[i] = o;
    }
    for (int i = tid; i < total; i += nth) {
        int s = segment_ids[i];
        if (i == 0 || segment_ids[i - 1] != s) starts[s] = i;
    }
}

// Pass 2: bf16 gather. 128-thread blocks = 2 waves (R9 shape); wave w does
// segment pair*2+w, batch b = bid & 7 (XCD pinning: verified R2). bf16 rows
// are 128 B -> lane = sub*8 + fq: sub (0..7) picks one of EIGHT rows per
// gather instruction, fq (0..7) the 16-B feature oct (8 bf16). Indices
// staged pre-scaled (idx*FEAT elem offset), broadcast via __shfl. Depth-8
// issue-then-drain sawtooth (verified R5); f32 accumulation.
__global__ __launch_bounds__(128, 8)
void genesets_pool_bf16_kernel(const unsigned short* __restrict__ bf, // [B][G][F] bf16
                               const int* __restrict__ flat_indices,
                               const int* __restrict__ starts,
                               const int* __restrict__ counts,
                               float* __restrict__ out,               // [B][S][F]
                               int num_segments)
{
    const int bid  = blockIdx.x;
    const int b    = bid & 7;                      // batch -> XCD
    const int wave = threadIdx.x >> 6;             // 0..1
    const int s    = (bid >> 3) * 2 + wave;        // segment
    const int lane = threadIdx.x & 63;
    const int sub  = lane >> 3;                    // 0..7: row within group of 8
    const int fq   = lane & 7;                     // 0..7: feature oct

    if (s >= num_segments) return;

    const int start = starts[s];
    const int cnt   = counts[s];

    // Stage all indices, pre-scaled to element offsets (cnt < 128).
    int off_a = (lane      < cnt) ? flat_indices[start + lane]      * FEAT : 0;
    int off_b = (lane + 64 < cnt) ? flat_indices[start + lane + 64] * FEAT : 0;

    const unsigned short* gbase = bf + (size_t)b * NUM_GENES * FEAT + fq * 8;

    float a0 = 0.f, a1 = 0.f, a2 = 0.f, a3 = 0.f;
    float a4 = 0.f, a5 = 0.f, a6 = 0.f, a7 = 0.f;

    const int kn8 = (cnt + 7) >> 3;                // groups of 8 rows, <= 12

    for (int c = 0; c < kn8; c += 8) {
        uint4 buf[8];
        #pragma unroll
        for (int p = 0; p < 8; ++p) {
            const int j = sub + 8 * (c + p);
            const int off = (j < 64) ? __shfl(off_a, j) : __shfl(off_b, j & 63);
            if (j < cnt) {
                buf[p] = *reinterpret_cast<const uint4*>(gbase + off);
            } else {
                buf[p] = make_uint4(0u, 0u, 0u, 0u);
            }
        }
        #pragma unroll
        for (int p = 0; p < 8; ++p) {
            a0 += __uint_as_float(buf[p].x << 16);
            a1 += __uint_as_float(buf[p].x & 0xFFFF0000u);
            a2 += __uint_as_float(buf[p].y << 16);
            a3 += __uint_as_float(buf[p].y & 0xFFFF0000u);
            a4 += __uint_as_float(buf[p].z << 16);
            a5 += __uint_as_float(buf[p].z & 0xFFFF0000u);
            a6 += __uint_as_float(buf[p].w << 16);
            a7 += __uint_as_float(buf[p].w & 0xFFFF0000u);
        }
    }

    // Reduce over the 8 sub-groups (lanes differing in bits 3..5).
    #pragma unroll
    for (int m = 8; m <= 32; m <<= 1) {
        a0 += __shfl_xor(a0, m); a1 += __shfl_xor(a1, m);
        a2 += __shfl_xor(a2, m); a3 += __shfl_xor(a3, m);
        a4 += __shfl_xor(a4, m); a5 += __shfl_xor(a5, m);
        a6 += __shfl_xor(a6, m); a7 += __shfl_xor(a7, m);
    }

    if (sub == 0) {                                 // lanes 0..7 -> 256 B row
        const float inv = 1.0f / (float)cnt;
        float* obase = out + ((size_t)b * num_segments + s) * FEAT + fq * 8;
        *reinterpret_cast<float4*>(obase)     = make_float4(a0 * inv, a1 * inv, a2 * inv, a3 * inv);
        *reinterpret_cast<float4*>(obase + 4) = make_float4(a4 * inv, a5 * inv, a6 * inv, a7 * inv);
    }
}

// -------- fallback path (R9, f32 gather) if d_ws is too small ------------
__global__ __launch_bounds__(256)
void find_starts_kernel(const int* __restrict__ segment_ids,
                        int* __restrict__ starts, int total)
{
    int i = blockIdx.x * 256 + threadIdx.x;
    if (i < total) {
        int s = segment_ids[i];
        if (i == 0 || segment_ids[i - 1] != s) starts[s] = i;
    }
}

__global__ __launch_bounds__(128, 8)
void genesets_pool_kernel(const float* __restrict__ gene,
                          const int*   __restrict__ flat_indices,
                          const int*   __restrict__ starts,
                          const int*   __restrict__ counts,
                          float*       __restrict__ out,
                          int num_segments)
{
    const int bid  = blockIdx.x;
    const int b    = bid & 7;
    const int wave = threadIdx.x >> 6;
    const int s    = (bid >> 3) * 2 + wave;
    const int lane = threadIdx.x & 63;
    const int sub  = lane >> 4;
    const int fq   = lane & 15;

    if (s >= num_segments) return;

    const int start = starts[s];
    const int cnt   = counts[s];

    int off_a = (lane      < cnt) ? flat_indices[start + lane]      * FEAT : 0;
    int off_b = (lane + 64 < cnt) ? flat_indices[start + lane + 64] * FEAT : 0;

    const float* gbase = gene + (size_t)b * NUM_GENES * FEAT + fq * 4;

    float4 acc = make_float4(0.f, 0.f, 0.f, 0.f);
    const int kn = (cnt + 3) >> 2;

    for (int c = 0; c < kn; c += 8) {
        float4 buf[8];
        #pragma unroll
        for (int p = 0; p < 8; ++p) {
            const int j = sub + 4 * (c + p);
            const int off = (j < 64) ? __shfl(off_a, j) : __shfl(off_b, j & 63);
            if (j < cnt) buf[p] = *reinterpret_cast<const float4*>(gbase + off);
            else         buf[p] = make_float4(0.f, 0.f, 0.f, 0.f);
        }
        #pragma unroll
        for (int p = 0; p < 8; ++p) {
            acc.x += buf[p].x; acc.y += buf[p].y;
            acc.z += buf[p].z; acc.w += buf[p].w;
        }
    }

    acc.x += __shfl_xor(acc.x, 16); acc.y += __shfl_xor(acc.y, 16);
    acc.z += __shfl_xor(acc.z, 16); acc.w += __shfl_xor(acc.w, 16);
    acc.x += __shfl_xor(acc.x, 32); acc.y += __shfl_xor(acc.y, 32);
    acc.z += __shfl_xor(acc.z, 32); acc.w += __shfl_xor(acc.w, 32);

    if (sub == 0) {
        const float inv = 1.0f / (float)cnt;
        float4 r = make_float4(acc.x * inv, acc.y * inv, acc.z * inv, acc.w * inv);
        *reinterpret_cast<float4*>(out + ((size_t)b * num_segments + s) * FEAT + fq * 4) = r;
    }
}

extern "C" void kernel_launch(void* const* d_in, const int* in_sizes, int n_in,
                              void* d_out, int out_size, void* d_ws, size_t ws_size,
                              hipStream_t stream)
{
    const float* gene         = (const float*)d_in[0];
    const int*   flat_indices = (const int*)d_in[1];
    const int*   segment_ids  = (const int*)d_in[2];
    const int*   counts       = (const int*)d_in[3];
    float*       out          = (float*)d_out;

    const int total        = in_sizes[1];
    const int num_segments = in_sizes[3];

    const size_t plane_bytes = (size_t)BATCH * NUM_GENES * FEAT * 2; // 20.48 MB
    const size_t need        = plane_bytes + (size_t)num_segments * 4;

    const int seg_pairs = (num_segments + 1) / 2;
    const int nblocks   = seg_pairs * BATCH;

    if (ws_size >= need) {
        unsigned short* bf     = (unsigned short*)d_ws;
        int*            starts = (int*)((char*)d_ws + plane_bytes);
        const int nconv8 = BATCH * NUM_GENES * FEAT / 8;  // 1,280,000

        convert_and_starts_kernel<<<2048, 256, 0, stream>>>(gene, segment_ids,
                                                            bf, starts, total, nconv8);
        genesets_pool_bf16_kernel<<<nblocks, 128, 0, stream>>>(bf, flat_indices, starts,
                                                               counts, out, num_segments);
    } else {
        int* starts = (int*)d_ws;
        find_starts_kernel<<<(total + 255) / 256, 256, 0, stream>>>(segment_ids, starts, total);
        genesets_pool_kernel<<<nblocks, 128, 0, stream>>>(gene, flat_indices, starts,
                                                          counts, out, num_segments);
    }
}

// Round 11
// 40.839 us; speedup vs baseline: 1.1521x; 1.1521x over previous
//
#include <hip/hip_runtime.h>

#define BATCH 8
#define NUM_GENES 20000
#define FEAT 64

__device__ __forceinline__ unsigned bf_round(float f) {
    unsigned u = __float_as_uint(f);
    return (u + 0x7FFFu + ((u >> 16) & 1u)) >> 16;   // RNE to bf16
}

// Pass 1 (fused): convert gene f32 -> bf16 plane in d_ws, XCD-LOCAL
// (block bid converts plane bid&7 only, so plane b is dirty ONLY in XCD
// b's L2 -- R10 showed all-XCD convert caused cross-XCD flush traffic:
// pool FETCH 43.5 MB ~= 2x plane size). Also finds segment starts.
__global__ __launch_bounds__(256)
void convert_and_starts_kernel(const float* __restrict__ gene,
                               const int*   __restrict__ segment_ids,
                               unsigned short* __restrict__ bf,
                               int* __restrict__ starts,
                               int total)
{
    const int b       = blockIdx.x & 7;                  // plane -> XCD
    const int pblk    = blockIdx.x >> 3;                 // block within plane
    const int pblkn   = gridDim.x >> 3;
    const int tid     = pblk * 256 + threadIdx.x;
    const int nth     = pblkn * 256;
    const int nconv8p = NUM_GENES * FEAT / 8;            // uint4 per plane

    const float4* g4 = reinterpret_cast<const float4*>(gene) + (size_t)b * NUM_GENES * FEAT / 4;
    uint4*        o4 = reinterpret_cast<uint4*>(bf)          + (size_t)b * NUM_GENES * FEAT / 8;
    for (int i = tid; i < nconv8p; i += nth) {           // 8 floats -> 8 bf16
        const float4 a = g4[2 * i];
        const float4 c = g4[2 * i + 1];
        uint4 o;
        o.x = bf_round(a.x) | (bf_round(a.y) << 16);
        o.y = bf_round(a.z) | (bf_round(a.w) << 16);
        o.z = bf_round(c.x) | (bf_round(c.y) << 16);
        o.w = bf_round(c.z) | (bf_round(c.w) << 16);
        o4[i] = o;
    }

    const int gtid = blockIdx.x * 256 + threadIdx.x;
    const int gnth = gridDim.x * 256;
    for (int i = gtid; i < total; i += gnth) {
        int s = segment_ids[i];
        if (i == 0 || segment_ids[i - 1] != s) starts[s] = i;
    }
}

// Pass 2: bf16 gather. 128-thread blocks = 2 waves; wave w does segment
// pair*2+w, batch b = bid & 7 (XCD pinning, verified R2). bf16 rows are
// 128 B -> lane = sub*8 + fq: sub (0..7) picks one of EIGHT rows per
// gather instruction, fq (0..7) the 16-B feature oct. cnt <= 89 so
// kn8 = ceil(cnt/8) <= 12: the WHOLE segment is one depth-12 issue burst
// (R5 lever, no loop). __launch_bounds__(128,4) caps at 128 VGPR so
// buf[12] (48 VGPR) stays register-resident -- R10's (128,8)/64-VGPR cap
// made the compiler serialize the pipeline (VGPR_Count=32, 43.9 us).
__global__ __launch_bounds__(128, 4)
void genesets_pool_bf16_kernel(const unsigned short* __restrict__ bf, // [B][G][F] bf16
                               const int* __restrict__ flat_indices,
                               const int* __restrict__ starts,
                               const int* __restrict__ counts,
                               float* __restrict__ out,               // [B][S][F]
                               int num_segments)
{
    const int bid  = blockIdx.x;
    const int b    = bid & 7;                      // batch -> XCD
    const int wave = threadIdx.x >> 6;             // 0..1
    const int s    = (bid >> 3) * 2 + wave;        // segment
    const int lane = threadIdx.x & 63;
    const int sub  = lane >> 3;                    // 0..7: row within group of 8
    const int fq   = lane & 7;                     // 0..7: feature oct

    if (s >= num_segments) return;

    const int start = starts[s];
    const int cnt   = counts[s];

    // Stage all indices, pre-scaled to element offsets (cnt < 128).
    int off_a = (lane      < cnt) ? flat_indices[start + lane]      * FEAT : 0;
    int off_b = (lane + 64 < cnt) ? flat_indices[start + lane + 64] * FEAT : 0;

    const unsigned short* gbase = bf + (size_t)b * NUM_GENES * FEAT + fq * 8;

    // Single issue burst of depth 12 covers any segment (kn8 <= 12).
    uint4 buf[12];
    #pragma unroll
    for (int p = 0; p < 12; ++p) {
        const int j = sub + 8 * p;
        const int off = (j < 64) ? __shfl(off_a, j) : __shfl(off_b, j & 63);
        if (j < cnt) {
            buf[p] = *reinterpret_cast<const uint4*>(gbase + off);
        } else {
            buf[p] = make_uint4(0u, 0u, 0u, 0u);
        }
    }

    float a0 = 0.f, a1 = 0.f, a2 = 0.f, a3 = 0.f;
    float a4 = 0.f, a5 = 0.f, a6 = 0.f, a7 = 0.f;
    #pragma unroll
    for (int p = 0; p < 12; ++p) {
        a0 += __uint_as_float(buf[p].x << 16);
        a1 += __uint_as_float(buf[p].x & 0xFFFF0000u);
        a2 += __uint_as_float(buf[p].y << 16);
        a3 += __uint_as_float(buf[p].y & 0xFFFF0000u);
        a4 += __uint_as_float(buf[p].z << 16);
        a5 += __uint_as_float(buf[p].z & 0xFFFF0000u);
        a6 += __uint_as_float(buf[p].w << 16);
        a7 += __uint_as_float(buf[p].w & 0xFFFF0000u);
    }

    // Reduce over the 8 sub-groups (lanes differing in bits 3..5).
    #pragma unroll
    for (int m = 8; m <= 32; m <<= 1) {
        a0 += __shfl_xor(a0, m); a1 += __shfl_xor(a1, m);
        a2 += __shfl_xor(a2, m); a3 += __shfl_xor(a3, m);
        a4 += __shfl_xor(a4, m); a5 += __shfl_xor(a5, m);
        a6 += __shfl_xor(a6, m); a7 += __shfl_xor(a7, m);
    }

    if (sub == 0) {                                 // lanes 0..7 -> 256 B row
        const float inv = 1.0f / (float)cnt;
        float* obase = out + ((size_t)b * num_segments + s) * FEAT + fq * 8;
        *reinterpret_cast<float4*>(obase)     = make_float4(a0 * inv, a1 * inv, a2 * inv, a3 * inv);
        *reinterpret_cast<float4*>(obase + 4) = make_float4(a4 * inv, a5 * inv, a6 * inv, a7 * inv);
    }
}

// -------- fallback path (R9, f32 gather) if d_ws is too small ------------
__global__ __launch_bounds__(256)
void find_starts_kernel(const int* __restrict__ segment_ids,
                        int* __restrict__ starts, int total)
{
    int i = blockIdx.x * 256 + threadIdx.x;
    if (i < total) {
        int s = segment_ids[i];
        if (i == 0 || segment_ids[i - 1] != s) starts[s] = i;
    }
}

__global__ __launch_bounds__(128, 8)
void genesets_pool_kernel(const float* __restrict__ gene,
                          const int*   __restrict__ flat_indices,
                          const int*   __restrict__ starts,
                          const int*   __restrict__ counts,
                          float*       __restrict__ out,
                          int num_segments)
{
    const int bid  = blockIdx.x;
    const int b    = bid & 7;
    const int wave = threadIdx.x >> 6;
    const int s    = (bid >> 3) * 2 + wave;
    const int lane = threadIdx.x & 63;
    const int sub  = lane >> 4;
    const int fq   = lane & 15;

    if (s >= num_segments) return;

    const int start = starts[s];
    const int cnt   = counts[s];

    int off_a = (lane      < cnt) ? flat_indices[start + lane]      * FEAT : 0;
    int off_b = (lane + 64 < cnt) ? flat_indices[start + lane + 64] * FEAT : 0;

    const float* gbase = gene + (size_t)b * NUM_GENES * FEAT + fq * 4;

    float4 acc = make_float4(0.f, 0.f, 0.f, 0.f);
    const int kn = (cnt + 3) >> 2;

    for (int c = 0; c < kn; c += 8) {
        float4 buf[8];
        #pragma unroll
        for (int p = 0; p < 8; ++p) {
            const int j = sub + 4 * (c + p);
            const int off = (j < 64) ? __shfl(off_a, j) : __shfl(off_b, j & 63);
            if (j < cnt) buf[p] = *reinterpret_cast<const float4*>(gbase + off);
            else         buf[p] = make_float4(0.f, 0.f, 0.f, 0.f);
        }
        #pragma unroll
        for (int p = 0; p < 8; ++p) {
            acc.x += buf[p].x; acc.y += buf[p].y;
            acc.z += buf[p].z; acc.w += buf[p].w;
        }
    }

    acc.x += __shfl_xor(acc.x, 16); acc.y += __shfl_xor(acc.y, 16);
    acc.z += __shfl_xor(acc.z, 16); acc.w += __shfl_xor(acc.w, 16);
    acc.x += __shfl_xor(acc.x, 32); acc.y += __shfl_xor(acc.y, 32);
    acc.z += __shfl_xor(acc.z, 32); acc.w += __shfl_xor(acc.w, 32);

    if (sub == 0) {
        const float inv = 1.0f / (float)cnt;
        float4 r = make_float4(acc.x * inv, acc.y * inv, acc.z * inv, acc.w * inv);
        *reinterpret_cast<float4*>(out + ((size_t)b * num_segments + s) * FEAT + fq * 4) = r;
    }
}

extern "C" void kernel_launch(void* const* d_in, const int* in_sizes, int n_in,
                              void* d_out, int out_size, void* d_ws, size_t ws_size,
                              hipStream_t stream)
{
    const float* gene         = (const float*)d_in[0];
    const int*   flat_indices = (const int*)d_in[1];
    const int*   segment_ids  = (const int*)d_in[2];
    const int*   counts       = (const int*)d_in[3];
    float*       out          = (float*)d_out;

    const int total        = in_sizes[1];
    const int num_segments = in_sizes[3];

    const size_t plane_bytes = (size_t)BATCH * NUM_GENES * FEAT * 2; // 20.48 MB
    const size_t need        = plane_bytes + (size_t)num_segments * 4;

    const int seg_pairs = (num_segments + 1) / 2;
    const int nblocks   = seg_pairs * BATCH;

    if (ws_size >= need) {
        unsigned short* bf     = (unsigned short*)d_ws;
        int*            starts = (int*)((char*)d_ws + plane_bytes);

        convert_and_starts_kernel<<<2048, 256, 0, stream>>>(gene, segment_ids,
                                                            bf, starts, total);
        genesets_pool_bf16_kernel<<<nblocks, 128, 0, stream>>>(bf, flat_indices, starts,
                                                               counts, out, num_segments);
    } else {
        int* starts = (int*)d_ws;
        find_starts_kernel<<<(total + 255) / 256, 256, 0, stream>>>(segment_ids, starts, total);
        genesets_pool_kernel<<<nblocks, 128, 0, stream>>>(gene, flat_indices, starts,
                                                          counts, out, num_segments);
    }
}